// Round 6
// baseline (1119.075 us; speedup 1.0000x reference)
//
#include <hip/hip_runtime.h>
#include <math.h>

#define SEQ    1024
#define DIM    1024
#define NH     16
#define HDIM   64
#define MLP    4096
#define NLAYER 4
#define BATCH  2
#define NTOK   (BATCH * SEQ)
#define LN_EPS 1e-5f

typedef unsigned short ushortx;
typedef __attribute__((ext_vector_type(8))) short bf16x8;
typedef __attribute__((ext_vector_type(8))) unsigned short u16x8;
typedef __attribute__((ext_vector_type(4))) float f32x4;

__device__ __forceinline__ float gelu_exact(float x) {
    return 0.5f * x * (1.0f + erff(x * 0.70710678118654752f));
}
// software RNE fp32->bf16 pack (verified R2/R4)
__device__ __forceinline__ unsigned int pack2bf(float a, float b) {
    union { float f; unsigned int u; } va, vb;
    va.f = a; vb.f = b;
    unsigned int ua = va.u + 0x7fffu + ((va.u >> 16) & 1u);
    unsigned int ub = vb.u + 0x7fffu + ((vb.u >> 16) & 1u);
    return (ua >> 16) | (ub & 0xffff0000u);
}
__device__ __forceinline__ ushortx bf16lo(float a) {
    return (ushortx)(pack2bf(a, 0.f) & 0xffffu);
}
__device__ __forceinline__ float bf2f(ushortx u) {
    union { unsigned int i; float f; } v; v.i = ((unsigned int)u) << 16; return v.f;
}
// async global->LDS 16B DMA: LDS dest = wave-uniform base + lane*16
__device__ __forceinline__ void gload16(const void* g, void* l) {
    __builtin_amdgcn_global_load_lds(
        (const __attribute__((address_space(1))) unsigned int*)g,
        (__attribute__((address_space(3))) unsigned int*)l, 16, 0, 0);
}

// ---------------------------------------------------------------------------
// Per-layer weight fp32 -> bf16 conversion into contiguous ws region.
// Segment layout (elems): wi1@0(3M) wo1@3M(1M) wi2@4M(3M) wo2@7M(1M)
//                         w1@8M(4M) w2@12M(4M). Total 16M elems.
// ---------------------------------------------------------------------------
__global__ __launch_bounds__(256)
void cvt_w(const float* __restrict__ s0, const float* __restrict__ s1,
           const float* __restrict__ s2, const float* __restrict__ s3,
           const float* __restrict__ s4, const float* __restrict__ s5,
           ushortx* __restrict__ dst)
{
    const size_t total = 4194304;  // in float4 units
    for (size_t g = (size_t)blockIdx.x * 256 + threadIdx.x; g < total;
         g += (size_t)gridDim.x * 256) {
        const float* src; size_t base;
        if      (g <  786432) { src = s0; base = 0; }
        else if (g < 1048576) { src = s1; base =  786432; }
        else if (g < 1835008) { src = s2; base = 1048576; }
        else if (g < 2097152) { src = s3; base = 1835008; }
        else if (g < 3145728) { src = s4; base = 2097152; }
        else                  { src = s5; base = 3145728; }
        float4 f = *(const float4*)(src + (g - base) * 4);
        ushort4 o = { bf16lo(f.x), bf16lo(f.y), bf16lo(f.z), bf16lo(f.w) };
        *(ushort4*)(dst + g * 4) = o;
    }
}

__global__ __launch_bounds__(256)
void init_x(const float* __restrict__ x0, float* __restrict__ xb,
            ushortx* __restrict__ xbf)
{
    const size_t i = (size_t)blockIdx.x * 256 + threadIdx.x;
    const float v = x0[i];
    xb[i] = v;
    xbf[i] = bf16lo(v);
}

// ---------------------------------------------------------------------------
// bf16 GEMM, global_load_lds staged + T3 2-phase pipeline: double-buffered
// LDS, prologue-stage tile 0, then per K-iter {issue DMA for tile kt+1 into
// buf^1 -> ds_read+MFMA on buf -> ONE __syncthreads()} (its implicit
// vmcnt(0) drain lands after a full compute phase covers load latency).
// Buffer safety: DMA into buf^1 is issued after the barrier that closed the
// iteration which last read buf^1.
// A:[M,K] bf16, W:[N,K] bf16, bias fp32. BK=64. Block=256=4 waves (2x2),
// wave tile (BM/2)x(BN/2). LDS rows UNPADDED [BM][64]; bank conflicts
// avoided by XOR swizzle on the per-lane GLOBAL source address (DMA dest
// must be linear) + same involution on the ds_read side:
//   LDS slot (row, c) holds global 16B-chunk  c ^ (row&7).
// kChunk: K-length this block reduces (split-K via blockIdx.z).
// MODE 0: fp32 out [M,N]; split-K plane z>0 -> Vout + (z-1)*M*N.
// MODE 1: gelu + bf16 out [M,N].
// MODE 2: qkv out — cols<2048 -> bf16 qk[tok][2048]; cols>=2048 -> vT
//         [(b*16+h)*64+d][SEQ] bf16 (packed 4-token 8B stores).
// MODE 3: qkv out, plain bf16 [tok][3*DIM] row-major.
// ---------------------------------------------------------------------------
template<int BM, int BN, int MODE>
__global__ __launch_bounds__(256)
void gemm_bf(const ushortx* __restrict__ A, const ushortx* __restrict__ W,
             const float* __restrict__ bias, void* __restrict__ Cout,
             void* __restrict__ Vout, int K, int N, int kChunk)
{
    constexpr int MT = BM / 32, NT = BN / 32;
    constexpr int AI = BM / 32, WI = BN / 32;   // 4KB staging calls per tile
    __shared__ ushortx As[2][BM * 64];
    __shared__ ushortx Ws[2][BN * 64];
    const int t = threadIdx.x;
    const int wave = t >> 6, lane = t & 63, quad = lane >> 4, l16 = lane & 15;
    const int wm = (wave >> 1) * (BM / 2);
    const int wn = (wave & 1) * (BN / 2);
    const int rowBase = blockIdx.y * BM, colBase = blockIdx.x * BN;
    const int kBase = blockIdx.z * kChunk;

    // staging coords: call i covers rows 32i + t/8; this thread's linear LDS
    // slot is chunk (t&7) of that row; it must fetch global chunk
    // (t&7) ^ (row&7)  (XOR swizzle involution).
    const int srow = t >> 3, schunk = t & 7;
    const ushortx* aSrc[AI];
    const ushortx* wSrc[WI];
    #pragma unroll
    for (int i = 0; i < AI; ++i) {
        const int r = srow + 32 * i;
        aSrc[i] = A + (size_t)(rowBase + r) * K + kBase + (schunk ^ (r & 7)) * 8;
    }
    #pragma unroll
    for (int i = 0; i < WI; ++i) {
        const int r = srow + 32 * i;
        wSrc[i] = W + (size_t)(colBase + r) * K + kBase + (schunk ^ (r & 7)) * 8;
    }
    const int dmaOff = wave * 1024;   // wave-uniform DMA dest byte offset

    f32x4 acc[MT][NT];
    #pragma unroll
    for (int mt = 0; mt < MT; ++mt)
        #pragma unroll
        for (int nt = 0; nt < NT; ++nt) acc[mt][nt] = (f32x4){0.f, 0.f, 0.f, 0.f};

    const int nIt = kChunk / 64;
    // prologue: stage tile 0 into buffer 0
    #pragma unroll
    for (int i = 0; i < AI; ++i)
        gload16(aSrc[i], (char*)As[0] + dmaOff + i * 4096);
    #pragma unroll
    for (int i = 0; i < WI; ++i)
        gload16(wSrc[i], (char*)Ws[0] + dmaOff + i * 4096);
    __syncthreads();           // drains vmcnt -> tile 0 valid

    int cur = 0;
    for (int kt = 0; kt < nIt; ++kt) {
        const int nxt = cur ^ 1;
        if (kt + 1 < nIt) {    // issue next tile; flies during MFMA below
            #pragma unroll
            for (int i = 0; i < AI; ++i)
                gload16(aSrc[i] + (kt + 1) * 64, (char*)As[nxt] + dmaOff + i * 4096);
            #pragma unroll
            for (int i = 0; i < WI; ++i)
                gload16(wSrc[i] + (kt + 1) * 64, (char*)Ws[nxt] + dmaOff + i * 4096);
        }
        #pragma unroll
        for (int kk = 0; kk < 2; ++kk) {
            bf16x8 af[MT], bfv[NT];
            #pragma unroll
            for (int mt = 0; mt < MT; ++mt) {
                const int r = wm + mt * 16 + l16;
                af[mt] = *(const bf16x8*)
                    &As[cur][r * 64 + (((kk * 4 + quad) ^ (r & 7)) * 8)];
            }
            #pragma unroll
            for (int nt = 0; nt < NT; ++nt) {
                const int r = wn + nt * 16 + l16;
                bfv[nt] = *(const bf16x8*)
                    &Ws[cur][r * 64 + (((kk * 4 + quad) ^ (r & 7)) * 8)];
            }
            #pragma unroll
            for (int mt = 0; mt < MT; ++mt)
                #pragma unroll
                for (int nt = 0; nt < NT; ++nt)
                    acc[mt][nt] = __builtin_amdgcn_mfma_f32_16x16x32_bf16(
                        af[mt], bfv[nt], acc[mt][nt], 0, 0, 0);
        }
        if (kt + 1 < nIt) __syncthreads();  // drain prefetch + sync reads
        cur = nxt;
    }
    // epilogue: D layout row = quad*4 + r, col = l16
    #pragma unroll
    for (int mt = 0; mt < MT; ++mt) {
        #pragma unroll
        for (int nt = 0; nt < NT; ++nt) {
            const int colTile = colBase + wn + nt * 16;
            const int col = colTile + l16;
            const float bv = (blockIdx.z == 0) ? bias[col] : 0.f;
            const int rbase = rowBase + wm + mt * 16 + quad * 4;
            if (MODE == 0) {
                float* C = (blockIdx.z == 0)
                    ? (float*)Cout
                    : (float*)Vout + (size_t)(blockIdx.z - 1) *
                          ((size_t)gridDim.y * BM) * N;
                #pragma unroll
                for (int r = 0; r < 4; ++r)
                    C[(size_t)(rbase + r) * N + col] = acc[mt][nt][r] + bv;
            } else if (MODE == 1) {
                ushortx* C = (ushortx*)Cout;
                #pragma unroll
                for (int r = 0; r < 4; ++r)
                    C[(size_t)(rbase + r) * N + col] = bf16lo(gelu_exact(acc[mt][nt][r] + bv));
            } else if (MODE == 3) {
                ushortx* C = (ushortx*)Cout;
                #pragma unroll
                for (int r = 0; r < 4; ++r)
                    C[(size_t)(rbase + r) * (3 * DIM) + col] = bf16lo(acc[mt][nt][r] + bv);
            } else {
                if (colTile < 2 * DIM) {
                    ushortx* C = (ushortx*)Cout;
                    #pragma unroll
                    for (int r = 0; r < 4; ++r)
                        C[(size_t)(rbase + r) * (2 * DIM) + col] = bf16lo(acc[mt][nt][r] + bv);
                } else {
                    ushortx* vt = (ushortx*)Vout;
                    const int cb = col - 2 * DIM;
                    const int hh = cb >> 6, dd = cb & 63;
                    const int bb = rbase >> 10, s0 = rbase & 1023;
                    ushort4 pk = { bf16lo(acc[mt][nt][0] + bv), bf16lo(acc[mt][nt][1] + bv),
                                   bf16lo(acc[mt][nt][2] + bv), bf16lo(acc[mt][nt][3] + bv) };
                    *(ushort4*)&vt[((size_t)((bb * 16 + hh) * 64 + dd) << 10) + s0] = pk;
                }
            }
        }
    }
}

// ---------------------------------------------------------------------------
// MFMA flash attention, bf16 inputs (qk[tok][2048], vT[(b*16+h)*64+d][SEQ]).
// Block = 4 waves, 64 queries of one (b,h). Output bf16 [tok][DIM].
// Register-prefetch + double-buffered K/V LDS: ONE barrier per k-tile,
// next-tile global loads in flight across the whole compute phase.
// ---------------------------------------------------------------------------
__global__ __launch_bounds__(256)
void attn_full(const ushortx* __restrict__ qk, const ushortx* __restrict__ vt,
               ushortx* __restrict__ outb)
{
    __shared__ ushortx Qs[64][72];
    __shared__ ushortx Ks[2][64][72];
    __shared__ ushortx VT[2][64][72];     // VT[.][d][key]
    __shared__ ushortx Ps[4][16][72];

    const int blk = blockIdx.x;
    const int q0 = (blk & 15) * 64;
    const int h  = (blk >> 4) & 15;
    const int b  = blk >> 8;
    const int t  = threadIdx.x;
    const int w = t >> 6, lane = t & 63;
    const int quad = lane >> 4, l16 = lane & 15;

    // cooperative-load coords: 512 16B-chunks = 64 rows x 8 chunks
    const int c0 = t,       r0 = c0 >> 3, c80 = (c0 & 7) * 8;
    const int c1 = t + 256, r1 = c1 >> 3, c81 = (c1 & 7) * 8;

    // Q -> LDS (once)
    *(u16x8*)&Qs[r0][c80] =
        *(const u16x8*)(qk + (size_t)(b * SEQ + q0 + r0) * (2 * DIM) + h * HDIM + c80);
    *(u16x8*)&Qs[r1][c81] =
        *(const u16x8*)(qk + (size_t)(b * SEQ + q0 + r1) * (2 * DIM) + h * HDIM + c81);

    const ushortx* kbase = qk + (size_t)(b * SEQ) * (2 * DIM) + DIM + h * HDIM;
    const ushortx* vbase = vt + ((size_t)((b * 16 + h) * 64) << 10);

    // prefetch tile 0 into registers
    u16x8 kR0 = *(const u16x8*)(kbase + (size_t)r0 * (2 * DIM) + c80);
    u16x8 kR1 = *(const u16x8*)(kbase + (size_t)r1 * (2 * DIM) + c81);
    u16x8 vR0 = *(const u16x8*)(vbase + ((size_t)r0 << 10) + c80);
    u16x8 vR1 = *(const u16x8*)(vbase + ((size_t)r1 << 10) + c81);

    __syncthreads();   // Q ready
    bf16x8 aq0 = *(const bf16x8*)&Qs[w * 16 + l16][quad * 8];
    bf16x8 aq1 = *(const bf16x8*)&Qs[w * 16 + l16][32 + quad * 8];

    float m_r[4] = {-1e30f, -1e30f, -1e30f, -1e30f};
    float l_r[4] = {0.f, 0.f, 0.f, 0.f};
    f32x4 Oa[4];
    #pragma unroll
    for (int nt = 0; nt < 4; ++nt) Oa[nt] = (f32x4){0.f, 0.f, 0.f, 0.f};

    int buf = 0;
    for (int kt = 0; kt < SEQ / 64; ++kt) {
        // stage current tile into LDS[buf] (safe: last reads of this buffer
        // were in iter kt-2, before iter kt-1's barrier)
        *(u16x8*)&Ks[buf][r0][c80] = kR0;
        *(u16x8*)&Ks[buf][r1][c81] = kR1;
        *(u16x8*)&VT[buf][r0][c80] = vR0;
        *(u16x8*)&VT[buf][r1][c81] = vR1;
        __syncthreads();

        if (kt + 1 < SEQ / 64) {   // next-tile loads overlap compute below
            const int k0 = (kt + 1) * 64;
            kR0 = *(const u16x8*)(kbase + (size_t)(k0 + r0) * (2 * DIM) + c80);
            kR1 = *(const u16x8*)(kbase + (size_t)(k0 + r1) * (2 * DIM) + c81);
            vR0 = *(const u16x8*)(vbase + ((size_t)r0 << 10) + k0 + c80);
            vR1 = *(const u16x8*)(vbase + ((size_t)r1 << 10) + k0 + c81);
        }

        f32x4 s[4];
        #pragma unroll
        for (int nt = 0; nt < 4; ++nt) {
            bf16x8 bk0 = *(const bf16x8*)&Ks[buf][nt * 16 + l16][quad * 8];
            bf16x8 bk1 = *(const bf16x8*)&Ks[buf][nt * 16 + l16][32 + quad * 8];
            s[nt] = __builtin_amdgcn_mfma_f32_16x16x32_bf16(aq0, bk0,
                        (f32x4){0.f, 0.f, 0.f, 0.f}, 0, 0, 0);
            s[nt] = __builtin_amdgcn_mfma_f32_16x16x32_bf16(aq1, bk1, s[nt], 0, 0, 0);
        }
        float tm[4], alpha[4];
        #pragma unroll
        for (int r = 0; r < 4; ++r) {
            float v = fmaxf(fmaxf(s[0][r], s[1][r]), fmaxf(s[2][r], s[3][r])) * 0.125f;
            #pragma unroll
            for (int off = 1; off < 16; off <<= 1) v = fmaxf(v, __shfl_xor(v, off));
            tm[r] = v;
        }
        #pragma unroll
        for (int r = 0; r < 4; ++r) {
            const float mn = fmaxf(m_r[r], tm[r]);
            alpha[r] = __expf(m_r[r] - mn);
            m_r[r] = mn;
        }
        float rs[4] = {0.f, 0.f, 0.f, 0.f};
        #pragma unroll
        for (int nt = 0; nt < 4; ++nt) {
            #pragma unroll
            for (int r = 0; r < 4; ++r) {
                const float p = __expf(s[nt][r] * 0.125f - m_r[r]);
                rs[r] += p;
                Ps[w][quad * 4 + r][nt * 16 + l16] = bf16lo(p);
            }
        }
        #pragma unroll
        for (int r = 0; r < 4; ++r) {
            float v = rs[r];
            #pragma unroll
            for (int off = 1; off < 16; off <<= 1) v += __shfl_xor(v, off);
            l_r[r] = l_r[r] * alpha[r] + v;
            #pragma unroll
            for (int nt = 0; nt < 4; ++nt) Oa[nt][r] *= alpha[r];
        }
        bf16x8 pa0 = *(const bf16x8*)&Ps[w][l16][quad * 8];
        bf16x8 pa1 = *(const bf16x8*)&Ps[w][l16][32 + quad * 8];
        #pragma unroll
        for (int nt = 0; nt < 4; ++nt) {
            bf16x8 bv0 = *(const bf16x8*)&VT[buf][nt * 16 + l16][quad * 8];
            bf16x8 bv1 = *(const bf16x8*)&VT[buf][nt * 16 + l16][32 + quad * 8];
            Oa[nt] = __builtin_amdgcn_mfma_f32_16x16x32_bf16(pa0, bv0, Oa[nt], 0, 0, 0);
            Oa[nt] = __builtin_amdgcn_mfma_f32_16x16x32_bf16(pa1, bv1, Oa[nt], 0, 0, 0);
        }
        buf ^= 1;
    }
    float inv[4];
    #pragma unroll
    for (int r = 0; r < 4; ++r) inv[r] = 1.f / l_r[r];
    #pragma unroll
    for (int r = 0; r < 4; ++r) {
        const size_t row = (size_t)(b * SEQ + q0 + w * 16 + quad * 4 + r);
        #pragma unroll
        for (int nt = 0; nt < 4; ++nt)
            outb[row * DIM + h * HDIM + nt * 16 + l16] = bf16lo(Oa[nt][r] * inv[r]);
    }
}

// ---------------------------------------------------------------------------
// Banded attention (|s-t| <= 2) over row-major qkv [tok][3*DIM] bf16.
// Thread = (s, octet-of-8-dims): 8 lanes per token, each owning 8 dims
// (one 16B load per row). 3-level shfl_xor butterfly for the dots.
// Block = 256 threads = 32 tokens of one (b,h); grid = B*NH*(SEQ/32).
// ---------------------------------------------------------------------------
__global__ __launch_bounds__(256)
void attn_band(const ushortx* __restrict__ qkv, ushortx* __restrict__ outb)
{
    const int blk = blockIdx.x;
    const int chunk = blk & (SEQ / 32 - 1);
    const int h = (blk >> 5) & (NH - 1);
    const int b = blk >> 9;
    const int tid = threadIdx.x;
    const int s = chunk * 32 + (tid >> 3);
    const int oct = tid & 7;
    const size_t base = (size_t)(b * SEQ) * (3 * DIM) + h * HDIM + oct * 8;

    // q fragment (8 dims)
    float qf[8];
    {
        u16x8 qv = *(const u16x8*)(qkv + base + (size_t)s * (3 * DIM));
        #pragma unroll
        for (int j = 0; j < 8; ++j) qf[j] = bf2f((ushortx)qv[j]);
    }

    float sc[5];
    #pragma unroll
    for (int o = 0; o < 5; ++o) {
        const int tt = s - 2 + o;
        const bool valid = ((unsigned)tt < SEQ);   // uniform within 8-lane group
        float d = 0.f;
        if (valid) {
            u16x8 kv = *(const u16x8*)(qkv + base + (size_t)tt * (3 * DIM) + DIM);
            #pragma unroll
            for (int j = 0; j < 8; ++j) d += qf[j] * bf2f((ushortx)kv[j]);
        }
        d += __shfl_xor(d, 1);
        d += __shfl_xor(d, 2);
        d += __shfl_xor(d, 4);
        sc[o] = valid ? d * 0.125f : -1e30f;
    }
    const float m = fmaxf(fmaxf(fmaxf(sc[0], sc[1]), fmaxf(sc[2], sc[3])), sc[4]);
    float p[5], sum = 0.f;
    #pragma unroll
    for (int o = 0; o < 5; ++o) { p[o] = __expf(sc[o] - m); sum += p[o]; }
    const float inv = 1.f / sum;

    float acc[8] = {0.f, 0.f, 0.f, 0.f, 0.f, 0.f, 0.f, 0.f};
    #pragma unroll
    for (int o = 0; o < 5; ++o) {
        const int tt = s - 2 + o;
        if ((unsigned)tt < SEQ) {
            u16x8 vv = *(const u16x8*)(qkv + base + (size_t)tt * (3 * DIM) + 2 * DIM);
            #pragma unroll
            for (int j = 0; j < 8; ++j) acc[j] += p[o] * bf2f((ushortx)vv[j]);
        }
    }
    unsigned int o01 = pack2bf(acc[0] * inv, acc[1] * inv);
    unsigned int o23 = pack2bf(acc[2] * inv, acc[3] * inv);
    unsigned int o45 = pack2bf(acc[4] * inv, acc[5] * inv);
    unsigned int o67 = pack2bf(acc[6] * inv, acc[7] * inv);
    uint4 st = { o01, o23, o45, o67 };
    *(uint4*)(outb + (size_t)(b * SEQ + s) * DIM + h * HDIM + oct * 8) = st;
}

// ---------------------------------------------------------------------------
// out = LN( x (+y) ) * g + b — fp32 out and/or bf16 out.
// ---------------------------------------------------------------------------
__global__ __launch_bounds__(256)
void add_ln(const float* __restrict__ x, const float* __restrict__ y,
            const float* __restrict__ g, const float* __restrict__ be,
            float* __restrict__ outf, ushortx* __restrict__ outb, int hasY)
{
    __shared__ float row[DIM];
    __shared__ float red[256];
    const int n = blockIdx.x;
    const int tid = threadIdx.x;
    float lsum = 0.f;
    for (int i = tid; i < DIM; i += 256) {
        float v = x[(size_t)n * DIM + i];
        if (hasY) v += y[(size_t)n * DIM + i];
        row[i] = v;
        lsum += v;
    }
    red[tid] = lsum;
    __syncthreads();
    for (int ofs = 128; ofs > 0; ofs >>= 1) {
        if (tid < ofs) red[tid] += red[tid + ofs];
        __syncthreads();
    }
    const float mu = red[0] * (1.f / DIM);
    __syncthreads();
    float lvar = 0.f;
    for (int i = tid; i < DIM; i += 256) {
        const float d = row[i] - mu;
        lvar += d * d;
    }
    red[tid] = lvar;
    __syncthreads();
    for (int ofs = 128; ofs > 0; ofs >>= 1) {
        if (tid < ofs) red[tid] += red[tid + ofs];
        __syncthreads();
    }
    const float rstd = rsqrtf(red[0] * (1.f / DIM) + LN_EPS);
    __syncthreads();
    for (int i = tid; i < DIM; i += 256) {
        const float o = (row[i] - mu) * rstd * g[i] + be[i];
        if (outf) outf[(size_t)n * DIM + i] = o;
        if (outb) outb[(size_t)n * DIM + i] = bf16lo(o);
    }
}

// out = a + p0 + p1 + p2 + p3 (split-K partial reduce + residual add)
__global__ __launch_bounds__(256)
void add_vec4(const float* __restrict__ a, const float* __restrict__ p0,
              const float* __restrict__ p1, const float* __restrict__ p2,
              const float* __restrict__ p3,
              float* __restrict__ outf, ushortx* __restrict__ outb)
{
    const size_t i = (size_t)blockIdx.x * 256 + threadIdx.x;
    const float v = a[i] + ((p0[i] + p1[i]) + (p2[i] + p3[i]));
    outf[i] = v;
    outb[i] = bf16lo(v);
}

// ---------------------------------------------------------------------------
extern "C" void kernel_launch(void* const* d_in, const int* in_sizes, int n_in,
                              void* d_out, int out_size, void* d_ws, size_t ws_size,
                              hipStream_t stream)
{
    const float* x0     = (const float*)d_in[0];
    const float* w_in1  = (const float*)d_in[1];
    const float* b_in1  = (const float*)d_in[2];
    const float* w_out1 = (const float*)d_in[3];
    const float* b_out1 = (const float*)d_in[4];
    const float* ln1_g  = (const float*)d_in[5];
    const float* ln1_b  = (const float*)d_in[6];
    const float* w_in2  = (const float*)d_in[7];
    const float* b_in2  = (const float*)d_in[8];
    const float* w_out2 = (const float*)d_in[9];
    const float* b_out2 = (const float*)d_in[10];
    const float* ln2_g  = (const float*)d_in[11];
    const float* ln2_b  = (const float*)d_in[12];
    const float* fw1    = (const float*)d_in[13];
    const float* fb1    = (const float*)d_in[14];
    const float* fw2    = (const float*)d_in[15];
    const float* fb2    = (const float*)d_in[16];
    const float* lnf_g  = (const float*)d_in[17];
    const float* lnf_b  = (const float*)d_in[18];
    float* out = (float*)d_out;

    char* W = (char*)d_ws;
    float*   xb    = (float*)(W);                          // 8 MB residual
    float*   t2    = (float*)(W + ((size_t)8  << 20));     // 8 MB proj/ffn2 out
    float*   attf  = (float*)(W + ((size_t)16 << 20));     // 8 MB attended fp32
    ushortx* actbf = (ushortx*)(W + ((size_t)24 << 20));   // 4 MB shared bf16 act
    ushortx* qkb   = (ushortx*)(W + ((size_t)28 << 20));   // 8 MB qk bf16 (MODE 2)
                                                           // or 12 MB qkv (MODE 3)
    ushortx* vtb   = (ushortx*)(W + ((size_t)36 << 20));   // 4 MB vT bf16
    ushortx* hbf   = (ushortx*)(W + ((size_t)28 << 20));   // 16 MB (alias qkb+vtb)
    ushortx* wbf   = (ushortx*)(W + ((size_t)44 << 20));   // 32 MB weights bf16
    // ffn2 split-K partial planes 1..3 (8 MB each): alias the wi1/wo1/wi2
    // bf16 weight region (abs 44-68 MB) — dead during steps 10-11, rewritten
    // by next layer's cvt_w. w2 (abs 68-76) stays live.
    float*   pk1   = (float*)(W + ((size_t)44 << 20));

    const size_t OFF_WI1 = 0,        OFF_WO1 = 3145728;
    const size_t OFF_WI2 = 4194304,  OFF_WO2 = 7340032;
    const size_t OFF_W1  = 8388608,  OFF_W2  = 12582912;

    init_x<<<dim3(NTOK * DIM / 256), dim3(256), 0, stream>>>(x0, xb, actbf);

    const dim3 blk(256);
    for (int l = 0; l < NLAYER; ++l) {
        const float* bi1 = b_in1  + (size_t)l * 3 * DIM;
        const float* bo1 = b_out1 + (size_t)l * DIM;
        const float* g1  = ln1_g  + (size_t)l * DIM;
        const float* be1 = ln1_b  + (size_t)l * DIM;
        const float* bi2 = b_in2  + (size_t)l * 3 * DIM;
        const float* bo2 = b_out2 + (size_t)l * DIM;
        const float* g2  = ln2_g  + (size_t)l * DIM;
        const float* be2 = ln2_b  + (size_t)l * DIM;
        const float* b1l = fb1    + (size_t)l * MLP;
        const float* b2l = fb2    + (size_t)l * DIM;

        cvt_w<<<dim3(2048), blk, 0, stream>>>(
            w_in1 + (size_t)l * 3 * DIM * DIM, w_out1 + (size_t)l * DIM * DIM,
            w_in2 + (size_t)l * 3 * DIM * DIM, w_out2 + (size_t)l * DIM * DIM,
            fw1 + (size_t)l * MLP * DIM, fw2 + (size_t)l * DIM * MLP, wbf);

        // 1. qkv1 (q,k -> qkb; v -> vtb transposed)
        gemm_bf<128, 128, 2><<<dim3(3 * DIM / 128, NTOK / 128), blk, 0, stream>>>(
            actbf, wbf + OFF_WI1, bi1, qkb, vtb, DIM, 0, DIM);
        // 2. full attention
        attn_full<<<dim3(BATCH * NH * (SEQ / 64)), blk, 0, stream>>>(qkb, vtb, actbf);
        // 3. proj1
        gemm_bf<64, 64, 0><<<dim3(DIM / 64, NTOK / 64), blk, 0, stream>>>(
            actbf, wbf + OFF_WO1, bo1, t2, nullptr, DIM, DIM, DIM);
        // 4. x = LN(x + proj)  (fp32 + bf16)
        add_ln<<<dim3(NTOK), blk, 0, stream>>>(xb, t2, g1, be1, xb, actbf, 1);
        // 5. qkv2 — row-major [tok][3*DIM] bf16 (band attn needs no vT)
        gemm_bf<128, 128, 3><<<dim3(3 * DIM / 128, NTOK / 128), blk, 0, stream>>>(
            actbf, wbf + OFF_WI2, bi2, qkb, nullptr, DIM, 3 * DIM, DIM);
        // 6. banded attention
        attn_band<<<dim3(BATCH * NH * (SEQ / 32)), blk, 0, stream>>>(qkb, actbf);
        // 7. proj2
        gemm_bf<64, 64, 0><<<dim3(DIM / 64, NTOK / 64), blk, 0, stream>>>(
            actbf, wbf + OFF_WO2, bo2, t2, nullptr, DIM, DIM, DIM);
        // 8. attended = LN(x + proj2)
        add_ln<<<dim3(NTOK), blk, 0, stream>>>(xb, t2, g2, be2, attf, actbf, 1);
        // 9. h = gelu(att @ fw1^T + fb1) -> bf16
        gemm_bf<128, 128, 1><<<dim3(MLP / 128, NTOK / 128), blk, 0, stream>>>(
            actbf, wbf + OFF_W1, b1l, hbf, nullptr, DIM, MLP, DIM);
        // 10. t2(+pk1..3) = h @ fw2^T + fb2 — split-K=4, 128^2 tiles
        gemm_bf<128, 128, 0><<<dim3(DIM / 128, NTOK / 128, 4), blk, 0, stream>>>(
            hbf, wbf + OFF_W2, b2l, t2, pk1, MLP, DIM, MLP / 4);
        // 11. x = attended + (t2 + pk1 + pk2 + pk3)
        add_vec4<<<dim3(NTOK * DIM / 256), blk, 0, stream>>>(
            attf, t2, pk1, pk1 + (size_t)NTOK * DIM, pk1 + (size_t)2 * NTOK * DIM,
            xb, actbf);
    }
    add_ln<<<dim3(NTOK), blk, 0, stream>>>(xb, nullptr, lnf_g, lnf_b, out, nullptr, 0);
}

// Round 7
// 1066.476 us; speedup vs baseline: 1.0493x; 1.0493x over previous
//
#include <hip/hip_runtime.h>
#include <math.h>

#define SEQ    1024
#define DIM    1024
#define NH     16
#define HDIM   64
#define MLP    4096
#define NLAYER 4
#define BATCH  2
#define NTOK   (BATCH * SEQ)
#define LN_EPS 1e-5f

typedef unsigned short ushortx;
typedef __attribute__((ext_vector_type(8))) short bf16x8;
typedef __attribute__((ext_vector_type(8))) unsigned short u16x8;
typedef __attribute__((ext_vector_type(4))) float f32x4;

__device__ __forceinline__ float gelu_exact(float x) {
    return 0.5f * x * (1.0f + erff(x * 0.70710678118654752f));
}
// software RNE fp32->bf16 pack (verified R2/R4)
__device__ __forceinline__ unsigned int pack2bf(float a, float b) {
    union { float f; unsigned int u; } va, vb;
    va.f = a; vb.f = b;
    unsigned int ua = va.u + 0x7fffu + ((va.u >> 16) & 1u);
    unsigned int ub = vb.u + 0x7fffu + ((vb.u >> 16) & 1u);
    return (ua >> 16) | (ub & 0xffff0000u);
}
__device__ __forceinline__ ushortx bf16lo(float a) {
    return (ushortx)(pack2bf(a, 0.f) & 0xffffu);
}
__device__ __forceinline__ float bf2f(ushortx u) {
    union { unsigned int i; float f; } v; v.i = ((unsigned int)u) << 16; return v.f;
}
// async global->LDS 16B DMA: LDS dest = wave-uniform base + lane*16
__device__ __forceinline__ void gload16(const void* g, void* l) {
    __builtin_amdgcn_global_load_lds(
        (const __attribute__((address_space(1))) unsigned int*)g,
        (__attribute__((address_space(3))) unsigned int*)l, 16, 0, 0);
}

// ---------------------------------------------------------------------------
// Per-layer weight fp32 -> bf16 conversion into contiguous ws region.
// Segment layout (elems): wi1@0(3M) wo1@3M(1M) wi2@4M(3M) wo2@7M(1M)
//                         w1@8M(4M) w2@12M(4M). Total 16M elems.
// ---------------------------------------------------------------------------
__global__ __launch_bounds__(256)
void cvt_w(const float* __restrict__ s0, const float* __restrict__ s1,
           const float* __restrict__ s2, const float* __restrict__ s3,
           const float* __restrict__ s4, const float* __restrict__ s5,
           ushortx* __restrict__ dst)
{
    const size_t total = 4194304;  // in float4 units
    for (size_t g = (size_t)blockIdx.x * 256 + threadIdx.x; g < total;
         g += (size_t)gridDim.x * 256) {
        const float* src; size_t base;
        if      (g <  786432) { src = s0; base = 0; }
        else if (g < 1048576) { src = s1; base =  786432; }
        else if (g < 1835008) { src = s2; base = 1048576; }
        else if (g < 2097152) { src = s3; base = 1835008; }
        else if (g < 3145728) { src = s4; base = 2097152; }
        else                  { src = s5; base = 3145728; }
        float4 f = *(const float4*)(src + (g - base) * 4);
        ushort4 o = { bf16lo(f.x), bf16lo(f.y), bf16lo(f.z), bf16lo(f.w) };
        *(ushort4*)(dst + g * 4) = o;
    }
}

__global__ __launch_bounds__(256)
void init_x(const float* __restrict__ x0, float* __restrict__ xb,
            ushortx* __restrict__ xbf)
{
    const size_t i = (size_t)blockIdx.x * 256 + threadIdx.x;
    const float v = x0[i];
    xb[i] = v;
    xbf[i] = bf16lo(v);
}

// ---------------------------------------------------------------------------
// bf16 GEMM, global_load_lds staged (m97 structure), BK=128 (halved sync
// points vs BK=64: same DMA bytes/MFMA count, half the barrier-drain pairs;
// occupancy unchanged — grid-capped at 2 blocks/CU).
// A:[M,K] bf16, W:[N,K] bf16, bias fp32. Block=256=4 waves (2x2), wave tile
// (BM/2)x(BN/2). LDS rows UNPADDED [BM][128]; bank conflicts avoided by XOR
// swizzle applied on the per-lane GLOBAL source address (DMA dest must be
// linear) and the same involution on the ds_read side:
//   LDS slot (row, c) holds global 16B-chunk  c ^ (row&15),  c in [0,16).
// Staging: call i covers rows 16i + t/16, chunk t&15; since 16i%16==0 the
// fetched chunk (t&15)^(row&15) = (t&15)^(t>>4) is per-thread constant.
// kChunk: K-length this block reduces (split-K via blockIdx.z); must be a
// multiple of 128.
// MODE 0: fp32 out [M,N]; split-K plane z>0 -> Vout + (z-1)*M*N.
// MODE 1: gelu + bf16 out [M,N].
// MODE 2: qkv out — cols<2048 -> bf16 qk[tok][2048]; cols>=2048 -> vT
//         [(b*16+h)*64+d][SEQ] bf16 (packed 4-token 8B stores).
// MODE 3: qkv out, plain bf16 [tok][3*DIM] row-major.
// ---------------------------------------------------------------------------
template<int BM, int BN, int MODE>
__global__ __launch_bounds__(256)
void gemm_bf(const ushortx* __restrict__ A, const ushortx* __restrict__ W,
             const float* __restrict__ bias, void* __restrict__ Cout,
             void* __restrict__ Vout, int K, int N, int kChunk)
{
    constexpr int MT = BM / 32, NT = BN / 32;
    constexpr int AI = BM / 16, WI = BN / 16;   // 4KB DMA calls per K-tile
    __shared__ ushortx As[BM * 128];
    __shared__ ushortx Ws[BN * 128];
    const int t = threadIdx.x;
    const int wave = t >> 6, lane = t & 63, quad = lane >> 4, l16 = lane & 15;
    const int wm = (wave >> 1) * (BM / 2);
    const int wn = (wave & 1) * (BN / 2);
    const int rowBase = blockIdx.y * BM, colBase = blockIdx.x * BN;
    const int kBase = blockIdx.z * kChunk;

    // staging base pointers (call 0); call i adds 16 rows = 16*K elems
    const int srow16 = t >> 4, sch = t & 15;
    const ushortx* aSrc0 = A + (size_t)(rowBase + srow16) * K + kBase
                             + (sch ^ srow16) * 8;
    const ushortx* wSrc0 = W + (size_t)(colBase + srow16) * K + kBase
                             + (sch ^ srow16) * 8;
    const int dmaOff = wave * 1024;   // wave-uniform DMA dest byte offset

    f32x4 acc[MT][NT];
    #pragma unroll
    for (int mt = 0; mt < MT; ++mt)
        #pragma unroll
        for (int nt = 0; nt < NT; ++nt) acc[mt][nt] = (f32x4){0.f, 0.f, 0.f, 0.f};

    const int nIt = kChunk / 128;
    for (int kt = 0; kt < nIt; ++kt) {
        if (kt) __syncthreads();   // prior compute reads done before overwrite
        #pragma unroll
        for (int i = 0; i < AI; ++i)
            gload16(aSrc0 + (size_t)16 * i * K + kt * 128,
                    (char*)As + dmaOff + i * 4096);
        #pragma unroll
        for (int i = 0; i < WI; ++i)
            gload16(wSrc0 + (size_t)16 * i * K + kt * 128,
                    (char*)Ws + dmaOff + i * 4096);
        __syncthreads();           // drains vmcnt -> tile valid in LDS
        #pragma unroll
        for (int kk = 0; kk < 4; ++kk) {
            bf16x8 af[MT], bfv[NT];
            #pragma unroll
            for (int mt = 0; mt < MT; ++mt) {
                const int r = wm + mt * 16 + l16;
                af[mt] = *(const bf16x8*)
                    &As[r * 128 + (((kk * 4 + quad) ^ (r & 15)) * 8)];
            }
            #pragma unroll
            for (int nt = 0; nt < NT; ++nt) {
                const int r = wn + nt * 16 + l16;
                bfv[nt] = *(const bf16x8*)
                    &Ws[r * 128 + (((kk * 4 + quad) ^ (r & 15)) * 8)];
            }
            #pragma unroll
            for (int mt = 0; mt < MT; ++mt)
                #pragma unroll
                for (int nt = 0; nt < NT; ++nt)
                    acc[mt][nt] = __builtin_amdgcn_mfma_f32_16x16x32_bf16(
                        af[mt], bfv[nt], acc[mt][nt], 0, 0, 0);
        }
    }
    // epilogue: D layout row = quad*4 + r, col = l16
    #pragma unroll
    for (int mt = 0; mt < MT; ++mt) {
        #pragma unroll
        for (int nt = 0; nt < NT; ++nt) {
            const int colTile = colBase + wn + nt * 16;
            const int col = colTile + l16;
            const float bv = (blockIdx.z == 0) ? bias[col] : 0.f;
            const int rbase = rowBase + wm + mt * 16 + quad * 4;
            if (MODE == 0) {
                float* C = (blockIdx.z == 0)
                    ? (float*)Cout
                    : (float*)Vout + (size_t)(blockIdx.z - 1) *
                          ((size_t)gridDim.y * BM) * N;
                #pragma unroll
                for (int r = 0; r < 4; ++r)
                    C[(size_t)(rbase + r) * N + col] = acc[mt][nt][r] + bv;
            } else if (MODE == 1) {
                ushortx* C = (ushortx*)Cout;
                #pragma unroll
                for (int r = 0; r < 4; ++r)
                    C[(size_t)(rbase + r) * N + col] = bf16lo(gelu_exact(acc[mt][nt][r] + bv));
            } else if (MODE == 3) {
                ushortx* C = (ushortx*)Cout;
                #pragma unroll
                for (int r = 0; r < 4; ++r)
                    C[(size_t)(rbase + r) * (3 * DIM) + col] = bf16lo(acc[mt][nt][r] + bv);
            } else {
                if (colTile < 2 * DIM) {
                    ushortx* C = (ushortx*)Cout;
                    #pragma unroll
                    for (int r = 0; r < 4; ++r)
                        C[(size_t)(rbase + r) * (2 * DIM) + col] = bf16lo(acc[mt][nt][r] + bv);
                } else {
                    ushortx* vt = (ushortx*)Vout;
                    const int cb = col - 2 * DIM;
                    const int hh = cb >> 6, dd = cb & 63;
                    const int bb = rbase >> 10, s0 = rbase & 1023;
                    ushort4 pk = { bf16lo(acc[mt][nt][0] + bv), bf16lo(acc[mt][nt][1] + bv),
                                   bf16lo(acc[mt][nt][2] + bv), bf16lo(acc[mt][nt][3] + bv) };
                    *(ushort4*)&vt[((size_t)((bb * 16 + hh) * 64 + dd) << 10) + s0] = pk;
                }
            }
        }
    }
}

// ---------------------------------------------------------------------------
// MFMA flash attention, bf16 inputs (qk[tok][2048], vT[(b*16+h)*64+d][SEQ]).
// Block = 4 waves, 64 queries of one (b,h). Output bf16 [tok][DIM].
// Register-prefetch + double-buffered K/V LDS: ONE barrier per k-tile,
// next-tile global loads in flight across the whole compute phase.
// ---------------------------------------------------------------------------
__global__ __launch_bounds__(256)
void attn_full(const ushortx* __restrict__ qk, const ushortx* __restrict__ vt,
               ushortx* __restrict__ outb)
{
    __shared__ ushortx Qs[64][72];
    __shared__ ushortx Ks[2][64][72];
    __shared__ ushortx VT[2][64][72];     // VT[.][d][key]
    __shared__ ushortx Ps[4][16][72];

    const int blk = blockIdx.x;
    const int q0 = (blk & 15) * 64;
    const int h  = (blk >> 4) & 15;
    const int b  = blk >> 8;
    const int t  = threadIdx.x;
    const int w = t >> 6, lane = t & 63;
    const int quad = lane >> 4, l16 = lane & 15;

    // cooperative-load coords: 512 16B-chunks = 64 rows x 8 chunks
    const int c0 = t,       r0 = c0 >> 3, c80 = (c0 & 7) * 8;
    const int c1 = t + 256, r1 = c1 >> 3, c81 = (c1 & 7) * 8;

    // Q -> LDS (once)
    *(u16x8*)&Qs[r0][c80] =
        *(const u16x8*)(qk + (size_t)(b * SEQ + q0 + r0) * (2 * DIM) + h * HDIM + c80);
    *(u16x8*)&Qs[r1][c81] =
        *(const u16x8*)(qk + (size_t)(b * SEQ + q0 + r1) * (2 * DIM) + h * HDIM + c81);

    const ushortx* kbase = qk + (size_t)(b * SEQ) * (2 * DIM) + DIM + h * HDIM;
    const ushortx* vbase = vt + ((size_t)((b * 16 + h) * 64) << 10);

    // prefetch tile 0 into registers
    u16x8 kR0 = *(const u16x8*)(kbase + (size_t)r0 * (2 * DIM) + c80);
    u16x8 kR1 = *(const u16x8*)(kbase + (size_t)r1 * (2 * DIM) + c81);
    u16x8 vR0 = *(const u16x8*)(vbase + ((size_t)r0 << 10) + c80);
    u16x8 vR1 = *(const u16x8*)(vbase + ((size_t)r1 << 10) + c81);

    __syncthreads();   // Q ready
    bf16x8 aq0 = *(const bf16x8*)&Qs[w * 16 + l16][quad * 8];
    bf16x8 aq1 = *(const bf16x8*)&Qs[w * 16 + l16][32 + quad * 8];

    float m_r[4] = {-1e30f, -1e30f, -1e30f, -1e30f};
    float l_r[4] = {0.f, 0.f, 0.f, 0.f};
    f32x4 Oa[4];
    #pragma unroll
    for (int nt = 0; nt < 4; ++nt) Oa[nt] = (f32x4){0.f, 0.f, 0.f, 0.f};

    int buf = 0;
    for (int kt = 0; kt < SEQ / 64; ++kt) {
        // stage current tile into LDS[buf] (safe: last reads of this buffer
        // were in iter kt-2, before iter kt-1's barrier)
        *(u16x8*)&Ks[buf][r0][c80] = kR0;
        *(u16x8*)&Ks[buf][r1][c81] = kR1;
        *(u16x8*)&VT[buf][r0][c80] = vR0;
        *(u16x8*)&VT[buf][r1][c81] = vR1;
        __syncthreads();

        if (kt + 1 < SEQ / 64) {   // next-tile loads overlap compute below
            const int k0 = (kt + 1) * 64;
            kR0 = *(const u16x8*)(kbase + (size_t)(k0 + r0) * (2 * DIM) + c80);
            kR1 = *(const u16x8*)(kbase + (size_t)(k0 + r1) * (2 * DIM) + c81);
            vR0 = *(const u16x8*)(vbase + ((size_t)r0 << 10) + k0 + c80);
            vR1 = *(const u16x8*)(vbase + ((size_t)r1 << 10) + k0 + c81);
        }

        f32x4 s[4];
        #pragma unroll
        for (int nt = 0; nt < 4; ++nt) {
            bf16x8 bk0 = *(const bf16x8*)&Ks[buf][nt * 16 + l16][quad * 8];
            bf16x8 bk1 = *(const bf16x8*)&Ks[buf][nt * 16 + l16][32 + quad * 8];
            s[nt] = __builtin_amdgcn_mfma_f32_16x16x32_bf16(aq0, bk0,
                        (f32x4){0.f, 0.f, 0.f, 0.f}, 0, 0, 0);
            s[nt] = __builtin_amdgcn_mfma_f32_16x16x32_bf16(aq1, bk1, s[nt], 0, 0, 0);
        }
        float tm[4], alpha[4];
        #pragma unroll
        for (int r = 0; r < 4; ++r) {
            float v = fmaxf(fmaxf(s[0][r], s[1][r]), fmaxf(s[2][r], s[3][r])) * 0.125f;
            #pragma unroll
            for (int off = 1; off < 16; off <<= 1) v = fmaxf(v, __shfl_xor(v, off));
            tm[r] = v;
        }
        #pragma unroll
        for (int r = 0; r < 4; ++r) {
            const float mn = fmaxf(m_r[r], tm[r]);
            alpha[r] = __expf(m_r[r] - mn);
            m_r[r] = mn;
        }
        float rs[4] = {0.f, 0.f, 0.f, 0.f};
        #pragma unroll
        for (int nt = 0; nt < 4; ++nt) {
            #pragma unroll
            for (int r = 0; r < 4; ++r) {
                const float p = __expf(s[nt][r] * 0.125f - m_r[r]);
                rs[r] += p;
                Ps[w][quad * 4 + r][nt * 16 + l16] = bf16lo(p);
            }
        }
        #pragma unroll
        for (int r = 0; r < 4; ++r) {
            float v = rs[r];
            #pragma unroll
            for (int off = 1; off < 16; off <<= 1) v += __shfl_xor(v, off);
            l_r[r] = l_r[r] * alpha[r] + v;
            #pragma unroll
            for (int nt = 0; nt < 4; ++nt) Oa[nt][r] *= alpha[r];
        }
        bf16x8 pa0 = *(const bf16x8*)&Ps[w][l16][quad * 8];
        bf16x8 pa1 = *(const bf16x8*)&Ps[w][l16][32 + quad * 8];
        #pragma unroll
        for (int nt = 0; nt < 4; ++nt) {
            bf16x8 bv0 = *(const bf16x8*)&VT[buf][nt * 16 + l16][quad * 8];
            bf16x8 bv1 = *(const bf16x8*)&VT[buf][nt * 16 + l16][32 + quad * 8];
            Oa[nt] = __builtin_amdgcn_mfma_f32_16x16x32_bf16(pa0, bv0, Oa[nt], 0, 0, 0);
            Oa[nt] = __builtin_amdgcn_mfma_f32_16x16x32_bf16(pa1, bv1, Oa[nt], 0, 0, 0);
        }
        buf ^= 1;
    }
    float inv[4];
    #pragma unroll
    for (int r = 0; r < 4; ++r) inv[r] = 1.f / l_r[r];
    #pragma unroll
    for (int r = 0; r < 4; ++r) {
        const size_t row = (size_t)(b * SEQ + q0 + w * 16 + quad * 4 + r);
        #pragma unroll
        for (int nt = 0; nt < 4; ++nt)
            outb[row * DIM + h * HDIM + nt * 16 + l16] = bf16lo(Oa[nt][r] * inv[r]);
    }
}

// ---------------------------------------------------------------------------
// Banded attention (|s-t| <= 2) over row-major qkv [tok][3*DIM] bf16.
// Thread = (s, octet-of-8-dims): 8 lanes per token, each owning 8 dims
// (one 16B load per row). 3-level shfl_xor butterfly for the dots.
// Block = 256 threads = 32 tokens of one (b,h); grid = B*NH*(SEQ/32).
// ---------------------------------------------------------------------------
__global__ __launch_bounds__(256)
void attn_band(const ushortx* __restrict__ qkv, ushortx* __restrict__ outb)
{
    const int blk = blockIdx.x;
    const int chunk = blk & (SEQ / 32 - 1);
    const int h = (blk >> 5) & (NH - 1);
    const int b = blk >> 9;
    const int tid = threadIdx.x;
    const int s = chunk * 32 + (tid >> 3);
    const int oct = tid & 7;
    const size_t base = (size_t)(b * SEQ) * (3 * DIM) + h * HDIM + oct * 8;

    // q fragment (8 dims)
    float qf[8];
    {
        u16x8 qv = *(const u16x8*)(qkv + base + (size_t)s * (3 * DIM));
        #pragma unroll
        for (int j = 0; j < 8; ++j) qf[j] = bf2f((ushortx)qv[j]);
    }

    float sc[5];
    #pragma unroll
    for (int o = 0; o < 5; ++o) {
        const int tt = s - 2 + o;
        const bool valid = ((unsigned)tt < SEQ);   // uniform within 8-lane group
        float d = 0.f;
        if (valid) {
            u16x8 kv = *(const u16x8*)(qkv + base + (size_t)tt * (3 * DIM) + DIM);
            #pragma unroll
            for (int j = 0; j < 8; ++j) d += qf[j] * bf2f((ushortx)kv[j]);
        }
        d += __shfl_xor(d, 1);
        d += __shfl_xor(d, 2);
        d += __shfl_xor(d, 4);
        sc[o] = valid ? d * 0.125f : -1e30f;
    }
    const float m = fmaxf(fmaxf(fmaxf(sc[0], sc[1]), fmaxf(sc[2], sc[3])), sc[4]);
    float p[5], sum = 0.f;
    #pragma unroll
    for (int o = 0; o < 5; ++o) { p[o] = __expf(sc[o] - m); sum += p[o]; }
    const float inv = 1.f / sum;

    float acc[8] = {0.f, 0.f, 0.f, 0.f, 0.f, 0.f, 0.f, 0.f};
    #pragma unroll
    for (int o = 0; o < 5; ++o) {
        const int tt = s - 2 + o;
        if ((unsigned)tt < SEQ) {
            u16x8 vv = *(const u16x8*)(qkv + base + (size_t)tt * (3 * DIM) + 2 * DIM);
            #pragma unroll
            for (int j = 0; j < 8; ++j) acc[j] += p[o] * bf2f((ushortx)vv[j]);
        }
    }
    unsigned int o01 = pack2bf(acc[0] * inv, acc[1] * inv);
    unsigned int o23 = pack2bf(acc[2] * inv, acc[3] * inv);
    unsigned int o45 = pack2bf(acc[4] * inv, acc[5] * inv);
    unsigned int o67 = pack2bf(acc[6] * inv, acc[7] * inv);
    uint4 st = { o01, o23, o45, o67 };
    *(uint4*)(outb + (size_t)(b * SEQ + s) * DIM + h * HDIM + oct * 8) = st;
}

// ---------------------------------------------------------------------------
// out = LN( x (+y) ) * g + b — fp32 out and/or bf16 out.
// ---------------------------------------------------------------------------
__global__ __launch_bounds__(256)
void add_ln(const float* __restrict__ x, const float* __restrict__ y,
            const float* __restrict__ g, const float* __restrict__ be,
            float* __restrict__ outf, ushortx* __restrict__ outb, int hasY)
{
    __shared__ float row[DIM];
    __shared__ float red[256];
    const int n = blockIdx.x;
    const int tid = threadIdx.x;
    float lsum = 0.f;
    for (int i = tid; i < DIM; i += 256) {
        float v = x[(size_t)n * DIM + i];
        if (hasY) v += y[(size_t)n * DIM + i];
        row[i] = v;
        lsum += v;
    }
    red[tid] = lsum;
    __syncthreads();
    for (int ofs = 128; ofs > 0; ofs >>= 1) {
        if (tid < ofs) red[tid] += red[tid + ofs];
        __syncthreads();
    }
    const float mu = red[0] * (1.f / DIM);
    __syncthreads();
    float lvar = 0.f;
    for (int i = tid; i < DIM; i += 256) {
        const float d = row[i] - mu;
        lvar += d * d;
    }
    red[tid] = lvar;
    __syncthreads();
    for (int ofs = 128; ofs > 0; ofs >>= 1) {
        if (tid < ofs) red[tid] += red[tid + ofs];
        __syncthreads();
    }
    const float rstd = rsqrtf(red[0] * (1.f / DIM) + LN_EPS);
    __syncthreads();
    for (int i = tid; i < DIM; i += 256) {
        const float o = (row[i] - mu) * rstd * g[i] + be[i];
        if (outf) outf[(size_t)n * DIM + i] = o;
        if (outb) outb[(size_t)n * DIM + i] = bf16lo(o);
    }
}

// out = a + p0 + p1 + p2 + p3 (split-K partial reduce + residual add)
__global__ __launch_bounds__(256)
void add_vec4(const float* __restrict__ a, const float* __restrict__ p0,
              const float* __restrict__ p1, const float* __restrict__ p2,
              const float* __restrict__ p3,
              float* __restrict__ outf, ushortx* __restrict__ outb)
{
    const size_t i = (size_t)blockIdx.x * 256 + threadIdx.x;
    const float v = a[i] + ((p0[i] + p1[i]) + (p2[i] + p3[i]));
    outf[i] = v;
    outb[i] = bf16lo(v);
}

// ---------------------------------------------------------------------------
extern "C" void kernel_launch(void* const* d_in, const int* in_sizes, int n_in,
                              void* d_out, int out_size, void* d_ws, size_t ws_size,
                              hipStream_t stream)
{
    const float* x0     = (const float*)d_in[0];
    const float* w_in1  = (const float*)d_in[1];
    const float* b_in1  = (const float*)d_in[2];
    const float* w_out1 = (const float*)d_in[3];
    const float* b_out1 = (const float*)d_in[4];
    const float* ln1_g  = (const float*)d_in[5];
    const float* ln1_b  = (const float*)d_in[6];
    const float* w_in2  = (const float*)d_in[7];
    const float* b_in2  = (const float*)d_in[8];
    const float* w_out2 = (const float*)d_in[9];
    const float* b_out2 = (const float*)d_in[10];
    const float* ln2_g  = (const float*)d_in[11];
    const float* ln2_b  = (const float*)d_in[12];
    const float* fw1    = (const float*)d_in[13];
    const float* fb1    = (const float*)d_in[14];
    const float* fw2    = (const float*)d_in[15];
    const float* fb2    = (const float*)d_in[16];
    const float* lnf_g  = (const float*)d_in[17];
    const float* lnf_b  = (const float*)d_in[18];
    float* out = (float*)d_out;

    char* W = (char*)d_ws;
    float*   xb    = (float*)(W);                          // 8 MB residual
    float*   t2    = (float*)(W + ((size_t)8  << 20));     // 8 MB proj/ffn2 out
    float*   attf  = (float*)(W + ((size_t)16 << 20));     // 8 MB attended fp32
    ushortx* actbf = (ushortx*)(W + ((size_t)24 << 20));   // 4 MB shared bf16 act
    ushortx* qkb   = (ushortx*)(W + ((size_t)28 << 20));   // 8 MB qk bf16 (MODE 2)
                                                           // or 12 MB qkv (MODE 3)
    ushortx* vtb   = (ushortx*)(W + ((size_t)36 << 20));   // 4 MB vT bf16
    ushortx* hbf   = (ushortx*)(W + ((size_t)28 << 20));   // 16 MB (alias qkb+vtb)
    ushortx* wbf   = (ushortx*)(W + ((size_t)44 << 20));   // 32 MB weights bf16
    // ffn2 split-K partial planes 1..3 (8 MB each): alias the wi1/wo1/wi2
    // bf16 weight region (abs 44-68 MB) — dead during steps 10-11, rewritten
    // by next layer's cvt_w. w2 (abs 68-76) stays live.
    float*   pk1   = (float*)(W + ((size_t)44 << 20));

    const size_t OFF_WI1 = 0,        OFF_WO1 = 3145728;
    const size_t OFF_WI2 = 4194304,  OFF_WO2 = 7340032;
    const size_t OFF_W1  = 8388608,  OFF_W2  = 12582912;

    init_x<<<dim3(NTOK * DIM / 256), dim3(256), 0, stream>>>(x0, xb, actbf);

    const dim3 blk(256);
    for (int l = 0; l < NLAYER; ++l) {
        const float* bi1 = b_in1  + (size_t)l * 3 * DIM;
        const float* bo1 = b_out1 + (size_t)l * DIM;
        const float* g1  = ln1_g  + (size_t)l * DIM;
        const float* be1 = ln1_b  + (size_t)l * DIM;
        const float* bi2 = b_in2  + (size_t)l * 3 * DIM;
        const float* bo2 = b_out2 + (size_t)l * DIM;
        const float* g2  = ln2_g  + (size_t)l * DIM;
        const float* be2 = ln2_b  + (size_t)l * DIM;
        const float* b1l = fb1    + (size_t)l * MLP;
        const float* b2l = fb2    + (size_t)l * DIM;

        cvt_w<<<dim3(2048), blk, 0, stream>>>(
            w_in1 + (size_t)l * 3 * DIM * DIM, w_out1 + (size_t)l * DIM * DIM,
            w_in2 + (size_t)l * 3 * DIM * DIM, w_out2 + (size_t)l * DIM * DIM,
            fw1 + (size_t)l * MLP * DIM, fw2 + (size_t)l * DIM * MLP, wbf);

        // 1. qkv1 (q,k -> qkb; v -> vtb transposed)
        gemm_bf<128, 128, 2><<<dim3(3 * DIM / 128, NTOK / 128), blk, 0, stream>>>(
            actbf, wbf + OFF_WI1, bi1, qkb, vtb, DIM, 0, DIM);
        // 2. full attention
        attn_full<<<dim3(BATCH * NH * (SEQ / 64)), blk, 0, stream>>>(qkb, vtb, actbf);
        // 3. proj1
        gemm_bf<64, 64, 0><<<dim3(DIM / 64, NTOK / 64), blk, 0, stream>>>(
            actbf, wbf + OFF_WO1, bo1, t2, nullptr, DIM, DIM, DIM);
        // 4. x = LN(x + proj)  (fp32 + bf16)
        add_ln<<<dim3(NTOK), blk, 0, stream>>>(xb, t2, g1, be1, xb, actbf, 1);
        // 5. qkv2 — row-major [tok][3*DIM] bf16 (band attn needs no vT)
        gemm_bf<128, 128, 3><<<dim3(3 * DIM / 128, NTOK / 128), blk, 0, stream>>>(
            actbf, wbf + OFF_WI2, bi2, qkb, nullptr, DIM, 3 * DIM, DIM);
        // 6. banded attention
        attn_band<<<dim3(BATCH * NH * (SEQ / 32)), blk, 0, stream>>>(qkb, actbf);
        // 7. proj2
        gemm_bf<64, 64, 0><<<dim3(DIM / 64, NTOK / 64), blk, 0, stream>>>(
            actbf, wbf + OFF_WO2, bo2, t2, nullptr, DIM, DIM, DIM);
        // 8. attended = LN(x + proj2)
        add_ln<<<dim3(NTOK), blk, 0, stream>>>(xb, t2, g2, be2, attf, actbf, 1);
        // 9. h = gelu(att @ fw1^T + fb1) -> bf16
        gemm_bf<128, 128, 1><<<dim3(MLP / 128, NTOK / 128), blk, 0, stream>>>(
            actbf, wbf + OFF_W1, b1l, hbf, nullptr, DIM, MLP, DIM);
        // 10. t2(+pk1..3) = h @ fw2^T + fb2 — split-K=4, 128^2 tiles
        gemm_bf<128, 128, 0><<<dim3(DIM / 128, NTOK / 128, 4), blk, 0, stream>>>(
            hbf, wbf + OFF_W2, b2l, t2, pk1, MLP, DIM, MLP / 4);
        // 11. x = attended + (t2 + pk1 + pk2 + pk3)
        add_vec4<<<dim3(NTOK * DIM / 256), blk, 0, stream>>>(
            attf, t2, pk1, pk1 + (size_t)NTOK * DIM, pk1 + (size_t)2 * NTOK * DIM,
            xb, actbf);
    }
    add_ln<<<dim3(NTOK), blk, 0, stream>>>(xb, nullptr, lnf_g, lnf_b, out, nullptr, 0);
}